// Round 17
// baseline (344.246 us; speedup 1.0000x reference)
//
#include <hip/hip_runtime.h>

#define N_NODES 100000
#define N_EDGES 1250000
#define IN_F 128
#define OUT_F 64

// ---------------------------------------------------------------------------
// Kernel 1: h = x @ W  (fp32, register-tiled 64x64). Unchanged from round 14.
// ---------------------------------------------------------------------------
#define TM 64
__global__ __launch_bounds__(256) void gemm3_k(const float* __restrict__ x,
                                               const float* __restrict__ w,
                                               float* __restrict__ h) {
    __shared__ float wlds[IN_F * OUT_F];   // 32 KB, [k][col]
    __shared__ float xlds[TM * IN_F];      // 32 KB, row-rotated float4 layout
    const int t = threadIdx.x;
    const int row0 = blockIdx.x * TM;

    const float4* w4p = (const float4*)w;
    float4* wl4 = (float4*)wlds;
    #pragma unroll
    for (int i = 0; i < 8; ++i) wl4[t + i * 256] = w4p[t + i * 256];

    #pragma unroll
    for (int i = 0; i < 8; ++i) {
        const int idx = t + i * 256;       // float4 index in 64x32 tile
        const int r   = idx >> 5;
        const int k4  = idx & 31;
        float4 v = make_float4(0.f, 0.f, 0.f, 0.f);
        if (row0 + r < N_NODES)
            v = ((const float4*)(x + (size_t)(row0 + r) * IN_F))[k4];
        const int k4s = (k4 + r) & 31;     // rotation swizzle
        *(float4*)&xlds[r * IN_F + k4s * 4] = v;
    }
    __syncthreads();

    const int colg = t & 15;
    const int rowg = t >> 4;
    float acc[4][4];
    #pragma unroll
    for (int i = 0; i < 4; ++i)
        #pragma unroll
        for (int j = 0; j < 4; ++j) acc[i][j] = 0.f;

    #pragma unroll 8
    for (int k4 = 0; k4 < 32; ++k4) {
        float4 wv[4];
        #pragma unroll
        for (int kk = 0; kk < 4; ++kk)
            wv[kk] = *(const float4*)&wlds[(k4 * 4 + kk) * OUT_F + colg * 4];
        #pragma unroll
        for (int i = 0; i < 4; ++i) {
            const int r = rowg * 4 + i;
            const int k4s = (k4 + r) & 31;           // same rotation on read
            const float4 xv = *(const float4*)&xlds[r * IN_F + k4s * 4];
            acc[i][0] += xv.x * wv[0].x + xv.y * wv[1].x + xv.z * wv[2].x + xv.w * wv[3].x;
            acc[i][1] += xv.x * wv[0].y + xv.y * wv[1].y + xv.z * wv[2].y + xv.w * wv[3].y;
            acc[i][2] += xv.x * wv[0].z + xv.y * wv[1].z + xv.z * wv[2].z + xv.w * wv[3].z;
            acc[i][3] += xv.x * wv[0].w + xv.y * wv[1].w + xv.z * wv[2].w + xv.w * wv[3].w;
        }
    }

    #pragma unroll
    for (int i = 0; i < 4; ++i) {
        const int r = row0 + rowg * 4 + i;
        if (r < N_NODES) {
            float4 v = make_float4(acc[i][0], acc[i][1], acc[i][2], acc[i][3]);
            *(float4*)&h[(size_t)r * OUT_F + colg * 4] = v;
        }
    }
}

// ---------------------------------------------------------------------------
// XCD-partitioned counting sort. vid(e) = (e>>8)&7 == (blockIdx&7) of the
// block that scatters edge e (256 edges/block; consecutive blocks round-robin
// across the 8 XCDs). CSR is vid-major: cnt8/pos8[vid][node]; pairs region
// for vid v is written ONLY by blocks with blockIdx&7==v -> one XCD -> its L2
// coalesces the 8B records into full lines (round-14 evidence: mixed-XCD
// scatter wrote 64B/edge = 80 MB for a 10 MB array).
// ---------------------------------------------------------------------------
#define NVID 8
#define M8 (NVID * N_NODES)                 // 800000

__global__ __launch_bounds__(256) void hist8_k(const int* __restrict__ dst,
                                               int* __restrict__ cnt8) {
    const int e = blockIdx.x * 256 + threadIdx.x;
    if (e >= N_EDGES) return;
    const int vid = (e >> 8) & (NVID - 1);
    atomicAdd(&cnt8[vid * N_NODES + dst[e]], 1);
}

// Generic 3-step exclusive scan over M elements (1024 per block).
__global__ __launch_bounds__(256) void scan1g_k(const int* __restrict__ in,
                                                int* __restrict__ out,
                                                int* __restrict__ bsum,
                                                const int M) {
    __shared__ int lds[256];
    const int t = threadIdx.x;
    const int base = blockIdx.x * 1024 + t * 4;
    int v0 = 0, v1 = 0, v2 = 0, v3 = 0;
    if (base + 0 < M) v0 = in[base + 0];
    if (base + 1 < M) v1 = in[base + 1];
    if (base + 2 < M) v2 = in[base + 2];
    if (base + 3 < M) v3 = in[base + 3];
    const int s = v0 + v1 + v2 + v3;
    lds[t] = s;
    __syncthreads();
    #pragma unroll
    for (int off = 1; off < 256; off <<= 1) {
        const int add = (t >= off) ? lds[t - off] : 0;
        __syncthreads();
        lds[t] += add;
        __syncthreads();
    }
    const int excl = lds[t] - s;
    if (base + 0 < M) out[base + 0] = excl;
    if (base + 1 < M) out[base + 1] = excl + v0;
    if (base + 2 < M) out[base + 2] = excl + v0 + v1;
    if (base + 3 < M) out[base + 3] = excl + v0 + v1 + v2;
    if (t == 255) bsum[blockIdx.x] = lds[t];
}

// Scan of up to 1024 block sums in one 256-thread block.
__global__ __launch_bounds__(256) void scan2g_k(int* __restrict__ bsum,
                                                const int m) {
    __shared__ int lds[256];
    const int t = threadIdx.x;
    const int base = t * 4;
    int v0 = 0, v1 = 0, v2 = 0, v3 = 0;
    if (base + 0 < m) v0 = bsum[base + 0];
    if (base + 1 < m) v1 = bsum[base + 1];
    if (base + 2 < m) v2 = bsum[base + 2];
    if (base + 3 < m) v3 = bsum[base + 3];
    const int s = v0 + v1 + v2 + v3;
    lds[t] = s;
    __syncthreads();
    #pragma unroll
    for (int off = 1; off < 256; off <<= 1) {
        const int add = (t >= off) ? lds[t - off] : 0;
        __syncthreads();
        lds[t] += add;
        __syncthreads();
    }
    const int excl = lds[t] - s;
    if (base + 0 < m) bsum[base + 0] = excl;
    if (base + 1 < m) bsum[base + 1] = excl + v0;
    if (base + 2 < m) bsum[base + 2] = excl + v0 + v1;
    if (base + 3 < m) bsum[base + 3] = excl + v0 + v1 + v2;
}

__global__ __launch_bounds__(256) void scan3g_k(int* __restrict__ pos8,
                                                const int* __restrict__ bsum,
                                                const int M) {
    const int i = blockIdx.x * 256 + threadIdx.x;
    if (i >= M) return;
    pos8[i] += bsum[i >> 10];
}

__global__ __launch_bounds__(256) void bucket8_k(const int* __restrict__ src,
                                                 const int* __restrict__ dst,
                                                 const float* __restrict__ ew,
                                                 int* __restrict__ pos8,
                                                 uint2* __restrict__ pairs) {
    const int e = blockIdx.x * 256 + threadIdx.x;
    if (e >= N_EDGES) return;
    const int vid = (e >> 8) & (NVID - 1);
    const int d = dst[e];
    const int p = atomicAdd(&pos8[vid * N_NODES + d], 1);
    pairs[p] = make_uint2((unsigned)src[e], __float_as_uint(ew[e]));
}

// ---------------------------------------------------------------------------
// Per-node gather-accumulate + fused finalize. Quarter-wave per node-slot as
// in the proven accum_k; each quarter walks its 2 vid sub-segments (avg 3.2
// edges, same trip count as the old q-strided loop). Segment start derived
// from cursor end: start = pos8 - cnt8. Count reduced alongside features.
// ---------------------------------------------------------------------------
__global__ __launch_bounds__(256) void accum8_k(const float* __restrict__ h,
                                                const uint2* __restrict__ pairs,
                                                const int* __restrict__ pos8,
                                                const int* __restrict__ cnt8,
                                                const float* __restrict__ bias,
                                                float* __restrict__ out) {
    const int node = blockIdx.x * 4 + (threadIdx.x >> 6);
    const int lane = threadIdx.x & 63;
    const int q  = lane >> 4;
    const int ql = lane & 15;

    float4 acc = make_float4(0.f, 0.f, 0.f, 0.f);
    int c_me = 0;
    #pragma unroll
    for (int vv = 0; vv < 2; ++vv) {
        const int idx = (2 * q + vv) * N_NODES + node;
        const int e1 = pos8[idx];
        const int c8 = cnt8[idx];
        c_me += c8;
        for (int i = e1 - c8; i < e1; ++i) {
            const uint2 pr = pairs[i];
            const float wgt = __uint_as_float(pr.y);
            const float4 hv = ((const float4*)(h + (size_t)pr.x * OUT_F))[ql];
            acc.x += hv.x * wgt;
            acc.y += hv.y * wgt;
            acc.z += hv.z * wgt;
            acc.w += hv.w * wgt;
        }
    }

    #pragma unroll
    for (int m = 16; m <= 32; m <<= 1) {
        acc.x += __shfl_xor(acc.x, m, 64);
        acc.y += __shfl_xor(acc.y, m, 64);
        acc.z += __shfl_xor(acc.z, m, 64);
        acc.w += __shfl_xor(acc.w, m, 64);
    }
    c_me += __shfl_xor(c_me, 16, 64);
    c_me += __shfl_xor(c_me, 32, 64);

    if (q == 0) {
        float cf = (float)c_me;
        if (cf < 1.f) cf = 1.f;
        const float inv = 1.0f / cf;
        const float4 b = ((const float4*)bias)[ql];
        float4 v;
        v.x = acc.x * inv + b.x;
        v.y = acc.y * inv + b.y;
        v.z = acc.z * inv + b.z;
        v.w = acc.w * inv + b.w;
        v.x = v.x > 0.f ? v.x : 0.f;
        v.y = v.y > 0.f ? v.y : 0.f;
        v.z = v.z > 0.f ? v.z : 0.f;
        v.w = v.w > 0.f ? v.w : 0.f;
        ((float4*)(out + (size_t)node * OUT_F))[ql] = v;
    }
}

// ---------------------------------------------------------------------------
// Fallback path (round-1 proven): atomic scatter + finalize. Used only if
// ws_size is too small for the sort path (needs h + cnt = 26 MB).
// ---------------------------------------------------------------------------
__global__ __launch_bounds__(256) void scatter_k(const float* __restrict__ h,
                                                 const float* __restrict__ ew,
                                                 const int* __restrict__ src,
                                                 const int* __restrict__ dst,
                                                 float* __restrict__ out,
                                                 float* __restrict__ cnt) {
    const int e = blockIdx.x * 4 + (threadIdx.x >> 6);
    if (e >= N_EDGES) return;
    const int lane = threadIdx.x & 63;
    const int   s = src[e];
    const int   d = dst[e];
    const float w = ew[e];
    const float v = h[(long)s * OUT_F + lane] * w;
    atomicAdd(&out[(long)d * OUT_F + lane], v);
    if (lane == 0) atomicAdd(&cnt[d], 1.0f);
}

__global__ __launch_bounds__(256) void final_k(float* __restrict__ out,
                                               const float* __restrict__ cnt,
                                               const float* __restrict__ bias) {
    const int tid = blockIdx.x * 256 + threadIdx.x;
    if (tid >= N_NODES * OUT_F) return;
    const int n = tid >> 6;
    const int f = tid & 63;
    float c = cnt[n];
    if (c < 1.0f) c = 1.0f;
    float v = out[tid] / c + bias[f];
    out[tid] = v > 0.0f ? v : 0.0f;
}

extern "C" void kernel_launch(void* const* d_in, const int* in_sizes, int n_in,
                              void* d_out, int out_size, void* d_ws, size_t ws_size,
                              hipStream_t stream) {
    const float* x    = (const float*)d_in[0];   // [N_NODES, IN_F]
    const float* w    = (const float*)d_in[1];   // [IN_F, OUT_F]
    const float* bias = (const float*)d_in[2];   // [OUT_F]
    const float* ew   = (const float*)d_in[3];   // [N_EDGES]
    const int*   ei   = (const int*)d_in[4];     // [2, N_EDGES] as int32

    float* out = (float*)d_out;
    const int* src = ei;
    const int* dst = ei + N_EDGES;

    // Workspace layout (bytes):
    char* ws = (char*)d_ws;
    float* h     = (float*)(ws);                          // 25.6 MB
    int*   cnt8  = (int*)(ws + 25600000);                 // 3.2 MB  [vid][node]
    int*   pos8  = (int*)(ws + 28800000);                 // 3.2 MB  [vid][node]
    int*   bsum  = (int*)(ws + 32000000);                 // 4 KB (782 ints)
    uint2* pairs = (uint2*)(ws + 32004096);               // 10 MB
    const size_t WS_NEEDED = 32004096 + (size_t)N_EDGES * sizeof(uint2);  // ~42 MB

    gemm3_k<<<(N_NODES + TM - 1) / TM, 256, 0, stream>>>(x, w, h);            // 1563

    if (ws_size >= WS_NEEDED) {
        // XCD-partitioned sorted-gather path: no output atomics.
        hipMemsetAsync(cnt8, 0, M8 * sizeof(int), stream);
        hist8_k<<<(N_EDGES + 255) / 256, 256, 0, stream>>>(dst, cnt8);        // 4883
        const int nsb = (M8 + 1023) / 1024;                                   // 782
        scan1g_k<<<nsb, 256, 0, stream>>>(cnt8, pos8, bsum, M8);
        scan2g_k<<<1, 256, 0, stream>>>(bsum, nsb);
        scan3g_k<<<(M8 + 255) / 256, 256, 0, stream>>>(pos8, bsum, M8);       // 3125
        bucket8_k<<<(N_EDGES + 255) / 256, 256, 0, stream>>>(src, dst, ew, pos8, pairs);
        accum8_k<<<N_NODES / 4, 256, 0, stream>>>(h, pairs, pos8, cnt8, bias, out);
    } else {
        // Fallback: atomic scatter (round-1 proven, 26 MB workspace).
        float* fcnt = (float*)(ws + 25600000);
        hipMemsetAsync(out, 0, (size_t)N_NODES * OUT_F * sizeof(float), stream);
        hipMemsetAsync(fcnt, 0, N_NODES * sizeof(float), stream);
        scatter_k<<<(N_EDGES + 3) / 4, 256, 0, stream>>>(h, ew, src, dst, out, fcnt);
        final_k<<<(N_NODES * OUT_F + 255) / 256, 256, 0, stream>>>(out, fcnt, bias);
    }
}

// Round 18
// 324.911 us; speedup vs baseline: 1.0595x; 1.0595x over previous
//
#include <hip/hip_runtime.h>

#define N_NODES 100000
#define N_EDGES 1250000
#define IN_F 128
#define OUT_F 64

__device__ __forceinline__ unsigned short f2bf(float f) {
    unsigned u = __float_as_uint(f);
    unsigned r = u + 0x7FFFu + ((u >> 16) & 1u);   // RNE
    return (unsigned short)(r >> 16);
}

// ---------------------------------------------------------------------------
// Kernel 1: h = x @ W  (fp32 compute, bf16 output; register-tiled 64x64).
// bf16 h halves the accum gather traffic (row = exactly 128B) and h writes.
// ---------------------------------------------------------------------------
#define TM 64
__global__ __launch_bounds__(256) void gemm3_k(const float* __restrict__ x,
                                               const float* __restrict__ w,
                                               unsigned short* __restrict__ hb) {
    __shared__ float wlds[IN_F * OUT_F];   // 32 KB, [k][col]
    __shared__ float xlds[TM * IN_F];      // 32 KB, row-rotated float4 layout
    const int t = threadIdx.x;
    const int row0 = blockIdx.x * TM;

    const float4* w4p = (const float4*)w;
    float4* wl4 = (float4*)wlds;
    #pragma unroll
    for (int i = 0; i < 8; ++i) wl4[t + i * 256] = w4p[t + i * 256];

    #pragma unroll
    for (int i = 0; i < 8; ++i) {
        const int idx = t + i * 256;       // float4 index in 64x32 tile
        const int r   = idx >> 5;
        const int k4  = idx & 31;
        float4 v = make_float4(0.f, 0.f, 0.f, 0.f);
        if (row0 + r < N_NODES)
            v = ((const float4*)(x + (size_t)(row0 + r) * IN_F))[k4];
        const int k4s = (k4 + r) & 31;     // rotation swizzle
        *(float4*)&xlds[r * IN_F + k4s * 4] = v;
    }
    __syncthreads();

    const int colg = t & 15;
    const int rowg = t >> 4;
    float acc[4][4];
    #pragma unroll
    for (int i = 0; i < 4; ++i)
        #pragma unroll
        for (int j = 0; j < 4; ++j) acc[i][j] = 0.f;

    #pragma unroll 8
    for (int k4 = 0; k4 < 32; ++k4) {
        float4 wv[4];
        #pragma unroll
        for (int kk = 0; kk < 4; ++kk)
            wv[kk] = *(const float4*)&wlds[(k4 * 4 + kk) * OUT_F + colg * 4];
        #pragma unroll
        for (int i = 0; i < 4; ++i) {
            const int r = rowg * 4 + i;
            const int k4s = (k4 + r) & 31;           // same rotation on read
            const float4 xv = *(const float4*)&xlds[r * IN_F + k4s * 4];
            acc[i][0] += xv.x * wv[0].x + xv.y * wv[1].x + xv.z * wv[2].x + xv.w * wv[3].x;
            acc[i][1] += xv.x * wv[0].y + xv.y * wv[1].y + xv.z * wv[2].y + xv.w * wv[3].y;
            acc[i][2] += xv.x * wv[0].z + xv.y * wv[1].z + xv.z * wv[2].z + xv.w * wv[3].z;
            acc[i][3] += xv.x * wv[0].w + xv.y * wv[1].w + xv.z * wv[2].w + xv.w * wv[3].w;
        }
    }

    #pragma unroll
    for (int i = 0; i < 4; ++i) {
        const int r = row0 + rowg * 4 + i;
        if (r < N_NODES) {
            ushort4 o;
            o.x = f2bf(acc[i][0]);
            o.y = f2bf(acc[i][1]);
            o.z = f2bf(acc[i][2]);
            o.w = f2bf(acc[i][3]);
            *(ushort4*)&hb[(size_t)r * OUT_F + colg * 4] = o;
        }
    }
}

// ---------------------------------------------------------------------------
// Counting sort of edges by dst (round-14 measured structure).
// ---------------------------------------------------------------------------
__global__ __launch_bounds__(256) void hist_k(const int* __restrict__ dst,
                                              int* __restrict__ cnt) {
    const int e = blockIdx.x * 256 + threadIdx.x;
    if (e >= N_EDGES) return;
    atomicAdd(&cnt[dst[e]], 1);
}

#define SCAN_B 1024   // elements per scan block (256 threads x 4)
__global__ __launch_bounds__(256) void scan1_k(const int* __restrict__ cnt,
                                               int* __restrict__ start,
                                               int* __restrict__ bsum) {
    __shared__ int lds[256];
    const int t = threadIdx.x;
    const int base = blockIdx.x * SCAN_B + t * 4;
    int v0 = 0, v1 = 0, v2 = 0, v3 = 0;
    if (base + 0 < N_NODES) v0 = cnt[base + 0];
    if (base + 1 < N_NODES) v1 = cnt[base + 1];
    if (base + 2 < N_NODES) v2 = cnt[base + 2];
    if (base + 3 < N_NODES) v3 = cnt[base + 3];
    const int s = v0 + v1 + v2 + v3;
    lds[t] = s;
    __syncthreads();
    #pragma unroll
    for (int off = 1; off < 256; off <<= 1) {
        const int add = (t >= off) ? lds[t - off] : 0;
        __syncthreads();
        lds[t] += add;
        __syncthreads();
    }
    const int excl = lds[t] - s;
    if (base + 0 < N_NODES) start[base + 0] = excl;
    if (base + 1 < N_NODES) start[base + 1] = excl + v0;
    if (base + 2 < N_NODES) start[base + 2] = excl + v0 + v1;
    if (base + 3 < N_NODES) start[base + 3] = excl + v0 + v1 + v2;
    if (t == 255) bsum[blockIdx.x] = lds[t];
}

#define NSCAN_BLOCKS ((N_NODES + SCAN_B - 1) / SCAN_B)   // 98
__global__ __launch_bounds__(128) void scan2_k(int* __restrict__ bsum) {
    __shared__ int lds[128];
    const int t = threadIdx.x;
    const int v = (t < NSCAN_BLOCKS) ? bsum[t] : 0;
    lds[t] = v;
    __syncthreads();
    #pragma unroll
    for (int off = 1; off < 128; off <<= 1) {
        const int add = (t >= off) ? lds[t - off] : 0;
        __syncthreads();
        lds[t] += add;
        __syncthreads();
    }
    if (t < NSCAN_BLOCKS) bsum[t] = lds[t] - v;   // exclusive
}

__global__ __launch_bounds__(256) void scan3_k(int* __restrict__ start,
                                               int* __restrict__ pos,
                                               const int* __restrict__ bsum) {
    const int i = blockIdx.x * 256 + threadIdx.x;
    if (i >= N_NODES) return;
    const int v = start[i] + bsum[i / SCAN_B];
    start[i] = v;
    pos[i] = v;
}

__global__ __launch_bounds__(256) void bucket_k(const int* __restrict__ src,
                                                const int* __restrict__ dst,
                                                const float* __restrict__ ew,
                                                int* __restrict__ pos,
                                                uint2* __restrict__ pairs) {
    const int e = blockIdx.x * 256 + threadIdx.x;
    if (e >= N_EDGES) return;
    const int d = dst[e];
    const int p = atomicAdd(&pos[d], 1);
    pairs[p] = make_uint2((unsigned)src[e], __float_as_uint(ew[e]));
}

// ---------------------------------------------------------------------------
// Per-node gather-accumulate (bf16 h) + fused finalize (div/bias/relu).
// Quarter-wave per edge-slot: lane ql loads uint2 = 4 bf16 (8B); a quarter's
// 16 lanes cover the 128B h row. Accumulate fp32; shfl reduce; q==0 writes.
// ---------------------------------------------------------------------------
__global__ __launch_bounds__(256) void accum_k(const unsigned short* __restrict__ hb,
                                               const uint2* __restrict__ pairs,
                                               const int* __restrict__ start,
                                               const int* __restrict__ cnt,
                                               const float* __restrict__ bias,
                                               float* __restrict__ out) {
    const int node = blockIdx.x * 4 + (threadIdx.x >> 6);
    const int lane = threadIdx.x & 63;
    const int q  = lane >> 4;
    const int ql = lane & 15;
    const int s0 = start[node];
    const int c  = cnt[node];

    float4 acc = make_float4(0.f, 0.f, 0.f, 0.f);
    for (int i = s0 + q; i < s0 + c; i += 4) {
        const uint2 pr = pairs[i];
        const float wgt = __uint_as_float(pr.y);
        const uint2 hv = ((const uint2*)(hb + (size_t)pr.x * OUT_F))[ql];
        const float f0 = __uint_as_float((hv.x & 0xFFFFu) << 16);
        const float f1 = __uint_as_float(hv.x & 0xFFFF0000u);
        const float f2 = __uint_as_float((hv.y & 0xFFFFu) << 16);
        const float f3 = __uint_as_float(hv.y & 0xFFFF0000u);
        acc.x += f0 * wgt;
        acc.y += f1 * wgt;
        acc.z += f2 * wgt;
        acc.w += f3 * wgt;
    }

    #pragma unroll
    for (int m = 16; m <= 32; m <<= 1) {
        acc.x += __shfl_xor(acc.x, m, 64);
        acc.y += __shfl_xor(acc.y, m, 64);
        acc.z += __shfl_xor(acc.z, m, 64);
        acc.w += __shfl_xor(acc.w, m, 64);
    }

    if (q == 0) {
        float cf = (float)c;
        if (cf < 1.f) cf = 1.f;
        const float inv = 1.0f / cf;
        const float4 b = ((const float4*)bias)[ql];
        float4 v;
        v.x = acc.x * inv + b.x;
        v.y = acc.y * inv + b.y;
        v.z = acc.z * inv + b.z;
        v.w = acc.w * inv + b.w;
        v.x = v.x > 0.f ? v.x : 0.f;
        v.y = v.y > 0.f ? v.y : 0.f;
        v.z = v.z > 0.f ? v.z : 0.f;
        v.w = v.w > 0.f ? v.w : 0.f;
        ((float4*)(out + (size_t)node * OUT_F))[ql] = v;
    }
}

// ---------------------------------------------------------------------------
// Fallback path: atomic scatter + finalize (bf16 h). Only if ws too small.
// ---------------------------------------------------------------------------
__global__ __launch_bounds__(256) void scatter_k(const unsigned short* __restrict__ hb,
                                                 const float* __restrict__ ew,
                                                 const int* __restrict__ src,
                                                 const int* __restrict__ dst,
                                                 float* __restrict__ out,
                                                 float* __restrict__ cnt) {
    const int e = blockIdx.x * 4 + (threadIdx.x >> 6);
    if (e >= N_EDGES) return;
    const int lane = threadIdx.x & 63;
    const int   s = src[e];
    const int   d = dst[e];
    const float w = ew[e];
    const float hv = __uint_as_float((unsigned)hb[(size_t)s * OUT_F + lane] << 16);
    atomicAdd(&out[(size_t)d * OUT_F + lane], hv * w);
    if (lane == 0) atomicAdd(&cnt[d], 1.0f);
}

__global__ __launch_bounds__(256) void final_k(float* __restrict__ out,
                                               const float* __restrict__ cnt,
                                               const float* __restrict__ bias) {
    const int tid = blockIdx.x * 256 + threadIdx.x;
    if (tid >= N_NODES * OUT_F) return;
    const int n = tid >> 6;
    const int f = tid & 63;
    float c = cnt[n];
    if (c < 1.0f) c = 1.0f;
    float v = out[tid] / c + bias[f];
    out[tid] = v > 0.0f ? v : 0.0f;
}

extern "C" void kernel_launch(void* const* d_in, const int* in_sizes, int n_in,
                              void* d_out, int out_size, void* d_ws, size_t ws_size,
                              hipStream_t stream) {
    const float* x    = (const float*)d_in[0];   // [N_NODES, IN_F]
    const float* w    = (const float*)d_in[1];   // [IN_F, OUT_F]
    const float* bias = (const float*)d_in[2];   // [OUT_F]
    const float* ew   = (const float*)d_in[3];   // [N_EDGES]
    const int*   ei   = (const int*)d_in[4];     // [2, N_EDGES] as int32

    float* out = (float*)d_out;
    const int* src = ei;
    const int* dst = ei + N_EDGES;

    // Workspace layout (bytes):
    char* ws = (char*)d_ws;
    unsigned short* hb = (unsigned short*)(ws);           // 12.8 MB (bf16 h)
    int*   cnt   = (int*)(ws + 13000000);                 // 400 KB
    int*   start = (int*)(ws + 13400000);                 // 400 KB
    int*   pos   = (int*)(ws + 13800000);                 // 400 KB
    int*   bsum  = (int*)(ws + 14200000);                 // 1 KB
    uint2* pairs = (uint2*)(ws + 14201024);               // 10 MB
    const size_t WS_NEEDED = 14201024 + (size_t)N_EDGES * sizeof(uint2);  // ~24 MB

    gemm3_k<<<(N_NODES + TM - 1) / TM, 256, 0, stream>>>(x, w, hb);           // 1563

    if (ws_size >= WS_NEEDED) {
        // Sorted gather path: no output atomics.
        hipMemsetAsync(cnt, 0, N_NODES * sizeof(int), stream);
        hist_k<<<(N_EDGES + 255) / 256, 256, 0, stream>>>(dst, cnt);          // 4883
        scan1_k<<<NSCAN_BLOCKS, 256, 0, stream>>>(cnt, start, bsum);          // 98
        scan2_k<<<1, 128, 0, stream>>>(bsum);
        scan3_k<<<(N_NODES + 255) / 256, 256, 0, stream>>>(start, pos, bsum); // 391
        bucket_k<<<(N_EDGES + 255) / 256, 256, 0, stream>>>(src, dst, ew, pos, pairs);
        accum_k<<<N_NODES / 4, 256, 0, stream>>>(hb, pairs, start, cnt, bias, out);
    } else {
        // Fallback: atomic scatter.
        float* fcnt = (float*)(ws + 13000000);
        hipMemsetAsync(out, 0, (size_t)N_NODES * OUT_F * sizeof(float), stream);
        hipMemsetAsync(fcnt, 0, N_NODES * sizeof(float), stream);
        scatter_k<<<(N_EDGES + 3) / 4, 256, 0, stream>>>(hb, ew, src, dst, out, fcnt);
        final_k<<<(N_NODES * OUT_F + 255) / 256, 256, 0, stream>>>(out, fcnt, bias);
    }
}